// Round 2
// baseline (2198.775 us; speedup 1.0000x reference)
//
#include <hip/hip_runtime.h>

typedef __attribute__((ext_vector_type(8))) short short8;
typedef __attribute__((ext_vector_type(4))) float floatx4;

__device__ __forceinline__ ushort f2bf(float f) {
    uint u = __builtin_bit_cast(uint, f);
    uint r = (u + 0x7FFFu + ((u >> 16) & 1u)) >> 16;   // RNE; inputs finite
    return (ushort)r;
}
__device__ __forceinline__ float bf2f(ushort u) {
    return __builtin_bit_cast(float, (uint)u << 16);
}

// Detect whether edge_index arrived as int64 (odd 32-bit words all zero) or int32.
__global__ void detect_i64(const uint* __restrict__ p, int* __restrict__ flag) {
    uint v = p[2 * threadIdx.x + 1];
    unsigned long long b = __ballot(v != 0u);
    if (threadIdx.x == 0) *flag = (b == 0ull) ? 1 : 0;
}

// Convert the (small) weight matrices fp32 -> bf16 once.
__global__ __launch_bounds__(256) void cvt_w(const float* __restrict__ W1,
                                             const float* __restrict__ W2,
                                             ushort* __restrict__ w1b,
                                             ushort* __restrict__ w2b, int n1, int n2) {
    int i = blockIdx.x * 256 + threadIdx.x;
    if (i < n1) w1b[i] = f2bf(W1[i]);
    else if (i < n1 + n2) w2b[i - n1] = f2bf(W2[i - n1]);
}

// Y[N,NOUT] = X[N,K] @ W[NOUT,K]^T   (X fp32 or bf16, W bf16, fp32 MFMA accum, bf16 out)
// Wave = 64 rows x all NOUT cols. W (<=64KB bf16) stays L1/L2 resident.
template<int K, int NOUT, bool XF32>
__global__ __launch_bounds__(256) void gemm_bt(const void* __restrict__ Xv,
                                               const ushort* __restrict__ W,
                                               ushort* __restrict__ Y, int N) {
    constexpr int NT = NOUT / 16;  // col tiles
    constexpr int KS = K / 32;     // k steps
    const int lane = threadIdx.x & 63;
    const int wv   = threadIdx.x >> 6;
    const int t    = lane & 15;    // A row / B col / D col within tile
    const int q    = lane >> 4;    // k-quad (A/B) / row-quad (D)
    const int rbase = (blockIdx.x * 4 + wv) * 64;
    if (rbase >= N) return;

    floatx4 acc[4][NT];
    #pragma unroll
    for (int a = 0; a < 4; a++)
        #pragma unroll
        for (int b = 0; b < NT; b++)
            #pragma unroll
            for (int i = 0; i < 4; i++) acc[a][b][i] = 0.f;

    for (int ks = 0; ks < KS; ks++) {
        short8 af[4];
        #pragma unroll
        for (int rt = 0; rt < 4; rt++) {
            int row = rbase + rt * 16 + t;
            if (row < N) {
                if (XF32) {
                    const float* p = (const float*)Xv + (long)row * K + ks * 32 + q * 8;
                    float4 a0 = *(const float4*)p;
                    float4 a1 = *(const float4*)(p + 4);
                    af[rt][0] = (short)f2bf(a0.x); af[rt][1] = (short)f2bf(a0.y);
                    af[rt][2] = (short)f2bf(a0.z); af[rt][3] = (short)f2bf(a0.w);
                    af[rt][4] = (short)f2bf(a1.x); af[rt][5] = (short)f2bf(a1.y);
                    af[rt][6] = (short)f2bf(a1.z); af[rt][7] = (short)f2bf(a1.w);
                } else {
                    af[rt] = *(const short8*)((const ushort*)Xv + (long)row * K + ks * 32 + q * 8);
                }
            } else {
                #pragma unroll
                for (int i = 0; i < 8; i++) af[rt][i] = 0;
            }
        }
        #pragma unroll
        for (int nt = 0; nt < NT; nt++) {
            short8 bf = *(const short8*)(W + (long)(nt * 16 + t) * K + ks * 32 + q * 8);
            #pragma unroll
            for (int rt = 0; rt < 4; rt++)
                acc[rt][nt] = __builtin_amdgcn_mfma_f32_16x16x32_bf16(af[rt], bf, acc[rt][nt], 0, 0, 0);
        }
    }
    // D layout: col = lane&15, row = (lane>>4)*4 + reg   [m89-verified]
    #pragma unroll
    for (int rt = 0; rt < 4; rt++) {
        #pragma unroll
        for (int j = 0; j < 4; j++) {
            int row = rbase + rt * 16 + q * 4 + j;
            if (row < N) {
                #pragma unroll
                for (int nt = 0; nt < NT; nt++)
                    Y[(long)row * NOUT + nt * 16 + t] = f2bf(acc[rt][nt][j]);
            }
        }
    }
}

// out[dst] += w_e * H[src]  over edges; F feats, F/2 lanes per edge (2 bf16 per lane).
template<int F>
__global__ __launch_bounds__(256) void scatter_edges(const ushort* __restrict__ H,
                                                     const void* __restrict__ eidx,
                                                     const float* __restrict__ ew,
                                                     float* __restrict__ outf,
                                                     int E, const int* __restrict__ flag) {
    constexpr int L = F / 2;
    long gtid = (long)blockIdx.x * 256 + threadIdx.x;
    long e = gtid / L;
    int  c = (int)(gtid % L);
    if (e >= E) return;
    int src, dst;
    if (*flag) {
        const long long* p = (const long long*)eidx;
        src = (int)p[e]; dst = (int)p[e + E];
    } else {
        const int* p = (const int*)eidx;
        src = p[e]; dst = p[e + E];
    }
    float w = ew[e];
    uint hv = *(const uint*)(H + (long)src * F + 2 * c);
    float f0 = bf2f((ushort)(hv & 0xffffu)) * w;
    float f1 = bf2f((ushort)(hv >> 16)) * w;
    float* o = outf + (long)dst * F + 2 * c;
    atomicAdd(o, f0);
    atomicAdd(o + 1, f1);
}

// relu(fp32) -> bf16
__global__ __launch_bounds__(256) void relu_cast(const float4* __restrict__ in,
                                                 ushort* __restrict__ out, long n4) {
    long i = (long)blockIdx.x * 256 + threadIdx.x;
    if (i >= n4) return;
    float4 v = in[i];
    ushort4 r;
    r.x = f2bf(fmaxf(v.x, 0.f)); r.y = f2bf(fmaxf(v.y, 0.f));
    r.z = f2bf(fmaxf(v.z, 0.f)); r.w = f2bf(fmaxf(v.w, 0.f));
    *(ushort4*)(out + i * 4) = r;
}

extern "C" void kernel_launch(void* const* d_in, const int* in_sizes, int n_in,
                              void* d_out, int out_size, void* d_ws, size_t ws_size,
                              hipStream_t stream) {
    const float* x   = (const float*)d_in[0];
    const void*  ei1 = d_in[1];
    const void*  ei2 = d_in[2];
    const float* ew1 = (const float*)d_in[3];
    const float* ew2 = (const float*)d_in[4];
    const float* W1  = (const float*)d_in[5];   // [128,256] fp32
    const float* W2  = (const float*)d_in[6];   // [64,128]  fp32

    const int N = in_sizes[0] / 256;   // 100000
    const int E = in_sizes[3];         // 1600000

    const size_t sz_out1f = (size_t)N * 128 * 4;   // fp32 accum layer1 (51.2 MB)
    const size_t sz_xw    = (size_t)N * 128 * 2;   // bf16 XW / H2      (25.6 MB)
    const size_t sz_h     = (size_t)N * 128 * 2;   // bf16 relu(h)      (25.6 MB)
    const size_t sz_w1b   = 128 * 256 * 2;
    const size_t sz_w2b   = 64 * 128 * 2;

    char* ws = (char*)d_ws;
    float*  out1f = (float*)ws;
    ushort* XW    = (ushort*)(ws + sz_out1f);
    ushort* hbuf  = (ushort*)(ws + sz_out1f + sz_xw);
    ushort* w1b   = (ushort*)(ws + sz_out1f + sz_xw + sz_h);
    ushort* w2b   = (ushort*)(ws + sz_out1f + sz_xw + sz_h + sz_w1b);
    int*    flag  = (int*)(ws + sz_out1f + sz_xw + sz_h + sz_w1b + sz_w2b);
    ushort* H2    = XW;   // XW dead after scatter1; reuse for layer-2 activations

    // ws and d_out are poisoned 0xAA before every launch -> zero the accumulators
    hipMemsetAsync(out1f, 0, sz_out1f, stream);
    hipMemsetAsync(d_out, 0, (size_t)out_size * 4, stream);
    detect_i64<<<1, 64, 0, stream>>>((const uint*)ei1, flag);
    cvt_w<<<(128 * 256 + 64 * 128 + 255) / 256, 256, 0, stream>>>(
        W1, W2, w1b, w2b, 128 * 256, 64 * 128);

    int gblocks = (N + 255) / 256;     // 391
    gemm_bt<256, 128, true><<<gblocks, 256, 0, stream>>>(x, w1b, XW, N);
    scatter_edges<128><<<(int)(((long)E * 64 + 255) / 256), 256, 0, stream>>>(
        XW, ei1, ew1, out1f, E, flag);
    relu_cast<<<(int)(((long)N * 128 / 4 + 255) / 256), 256, 0, stream>>>(
        (const float4*)out1f, hbuf, (long)N * 128 / 4);
    gemm_bt<128, 64, false><<<gblocks, 256, 0, stream>>>(hbuf, w2b, H2, N);
    scatter_edges<64><<<(int)(((long)E * 32 + 255) / 256), 256, 0, stream>>>(
        H2, ei2, ew2, (float*)d_out, E, flag);
}

// Round 3
// 843.464 us; speedup vs baseline: 2.6068x; 2.6068x over previous
//
#include <hip/hip_runtime.h>

typedef __attribute__((ext_vector_type(8))) short short8;
typedef __attribute__((ext_vector_type(4))) float floatx4;

__device__ __forceinline__ ushort f2bf(float f) {
    uint u = __builtin_bit_cast(uint, f);
    uint r = (u + 0x7FFFu + ((u >> 16) & 1u)) >> 16;   // RNE; inputs finite
    return (ushort)r;
}
__device__ __forceinline__ float bf2f(ushort u) {
    return __builtin_bit_cast(float, (uint)u << 16);
}

// Detect whether edge_index arrived as int64 (odd 32-bit words all zero) or int32.
__global__ void detect_i64(const uint* __restrict__ p, int* __restrict__ flag) {
    uint v = p[2 * threadIdx.x + 1];
    unsigned long long b = __ballot(v != 0u);
    if (threadIdx.x == 0) *flag = (b == 0ull) ? 1 : 0;
}

// Convert the (small) weight matrices fp32 -> bf16 once.
__global__ __launch_bounds__(256) void cvt_w(const float* __restrict__ W1,
                                             const float* __restrict__ W2,
                                             ushort* __restrict__ w1b,
                                             ushort* __restrict__ w2b, int n1, int n2) {
    int i = blockIdx.x * 256 + threadIdx.x;
    if (i < n1) w1b[i] = f2bf(W1[i]);
    else if (i < n1 + n2) w2b[i - n1] = f2bf(W2[i - n1]);
}

// Y[N,NOUT] = X[N,K] @ W[NOUT,K]^T   (X fp32 or bf16, W bf16, fp32 MFMA accum, bf16 out)
template<int K, int NOUT, bool XF32>
__global__ __launch_bounds__(256) void gemm_bt(const void* __restrict__ Xv,
                                               const ushort* __restrict__ W,
                                               ushort* __restrict__ Y, int N) {
    constexpr int NT = NOUT / 16;
    constexpr int KS = K / 32;
    const int lane = threadIdx.x & 63;
    const int wv   = threadIdx.x >> 6;
    const int t    = lane & 15;
    const int q    = lane >> 4;
    const int rbase = (blockIdx.x * 4 + wv) * 64;
    if (rbase >= N) return;

    floatx4 acc[4][NT];
    #pragma unroll
    for (int a = 0; a < 4; a++)
        #pragma unroll
        for (int b = 0; b < NT; b++)
            #pragma unroll
            for (int i = 0; i < 4; i++) acc[a][b][i] = 0.f;

    for (int ks = 0; ks < KS; ks++) {
        short8 af[4];
        #pragma unroll
        for (int rt = 0; rt < 4; rt++) {
            int row = rbase + rt * 16 + t;
            if (row < N) {
                if (XF32) {
                    const float* p = (const float*)Xv + (long)row * K + ks * 32 + q * 8;
                    float4 a0 = *(const float4*)p;
                    float4 a1 = *(const float4*)(p + 4);
                    af[rt][0] = (short)f2bf(a0.x); af[rt][1] = (short)f2bf(a0.y);
                    af[rt][2] = (short)f2bf(a0.z); af[rt][3] = (short)f2bf(a0.w);
                    af[rt][4] = (short)f2bf(a1.x); af[rt][5] = (short)f2bf(a1.y);
                    af[rt][6] = (short)f2bf(a1.z); af[rt][7] = (short)f2bf(a1.w);
                } else {
                    af[rt] = *(const short8*)((const ushort*)Xv + (long)row * K + ks * 32 + q * 8);
                }
            } else {
                #pragma unroll
                for (int i = 0; i < 8; i++) af[rt][i] = 0;
            }
        }
        #pragma unroll
        for (int nt = 0; nt < NT; nt++) {
            short8 bf = *(const short8*)(W + (long)(nt * 16 + t) * K + ks * 32 + q * 8);
            #pragma unroll
            for (int rt = 0; rt < 4; rt++)
                acc[rt][nt] = __builtin_amdgcn_mfma_f32_16x16x32_bf16(af[rt], bf, acc[rt][nt], 0, 0, 0);
        }
    }
    #pragma unroll
    for (int rt = 0; rt < 4; rt++) {
        #pragma unroll
        for (int j = 0; j < 4; j++) {
            int row = rbase + rt * 16 + q * 4 + j;
            if (row < N) {
                #pragma unroll
                for (int nt = 0; nt < NT; nt++)
                    Y[(long)row * NOUT + nt * 16 + t] = f2bf(acc[rt][nt][j]);
            }
        }
    }
}

// ---- CSR build ----
__global__ __launch_bounds__(256) void hist_dst(const void* __restrict__ eidx,
                                                int* __restrict__ deg, int E,
                                                const int* __restrict__ flag) {
    int e = blockIdx.x * 256 + threadIdx.x;
    if (e >= E) return;
    int dst;
    if (*flag) dst = (int)((const long long*)eidx)[e + E];
    else       dst = ((const int*)eidx)[e + E];
    atomicAdd(deg + dst, 1);
}

__global__ __launch_bounds__(256) void block_sum(const int* __restrict__ deg,
                                                 int* __restrict__ bsum, int N) {
    __shared__ int s[4];
    int i = blockIdx.x * 256 + threadIdx.x;
    int v = (i < N) ? deg[i] : 0;
    #pragma unroll
    for (int off = 32; off; off >>= 1) v += __shfl_down(v, off, 64);
    int wv = threadIdx.x >> 6;
    if ((threadIdx.x & 63) == 0) s[wv] = v;
    __syncthreads();
    if (threadIdx.x == 0) bsum[blockIdx.x] = s[0] + s[1] + s[2] + s[3];
}

__global__ __launch_bounds__(512) void scan_bsum(const int* __restrict__ bsum,
                                                 int* __restrict__ boff, int nb) {
    __shared__ int s[512];
    int t = threadIdx.x;
    s[t] = (t < nb) ? bsum[t] : 0;
    __syncthreads();
    for (int off = 1; off < 512; off <<= 1) {
        int v = (t >= off) ? s[t - off] : 0;
        __syncthreads();
        s[t] += v;
        __syncthreads();
    }
    if (t < nb) boff[t] = (t == 0) ? 0 : s[t - 1];
}

__global__ __launch_bounds__(256) void scan_final(const int* __restrict__ deg,
                                                  const int* __restrict__ boff,
                                                  int* __restrict__ rowptr, int N, int E) {
    __shared__ int s[256];
    int b = blockIdx.x, t = threadIdx.x;
    int i = b * 256 + t;
    s[t] = (i < N) ? deg[i] : 0;
    __syncthreads();
    for (int off = 1; off < 256; off <<= 1) {
        int v = (t >= off) ? s[t - off] : 0;
        __syncthreads();
        s[t] += v;
        __syncthreads();
    }
    if (i < N) rowptr[i] = boff[b] + (t ? s[t - 1] : 0);
    if (b == 0 && t == 0) rowptr[N] = E;
}

__global__ __launch_bounds__(256) void fill_pairs(const void* __restrict__ eidx,
                                                  const float* __restrict__ ew,
                                                  int* __restrict__ cursor,
                                                  int2* __restrict__ pairs, int E,
                                                  const int* __restrict__ flag) {
    int e = blockIdx.x * 256 + threadIdx.x;
    if (e >= E) return;
    int src, dst;
    if (*flag) {
        const long long* p = (const long long*)eidx;
        src = (int)p[e]; dst = (int)p[e + E];
    } else {
        const int* p = (const int*)eidx;
        src = p[e]; dst = p[e + E];
    }
    int pos = atomicAdd(cursor + dst, 1);
    pairs[pos] = make_int2(src, __builtin_bit_cast(int, ew[e]));
}

// ---- Pull gather: out[i] = sum_e w_e * H[src_e]  (fp32 accum in regs) ----
// F feats; L = F/2 lanes per node (2 bf16 feats per lane); 64/L nodes per wave.
template<int F, bool RELU, bool BF16OUT>
__global__ __launch_bounds__(256) void gather_nodes(const ushort* __restrict__ H,
                                                    const int2* __restrict__ pairs,
                                                    const int* __restrict__ rowptr,
                                                    void* __restrict__ out, int N) {
    constexpr int L = F / 2;
    constexpr int NPW = 64 / L;
    int wave = (blockIdx.x * 256 + threadIdx.x) >> 6;
    int lane = threadIdx.x & 63;
    int node = wave * NPW + lane / L;
    int c = lane % L;
    if (node >= N) return;
    int s = rowptr[node], e = rowptr[node + 1];
    float a0 = 0.f, a1 = 0.f;
    for (int i = s; i < e; i++) {
        int2 p = pairs[i];                       // same addr across lane-group -> broadcast
        float w = __builtin_bit_cast(float, p.y);
        uint hv = *(const uint*)(H + (long)p.x * F + 2 * c);
        a0 += w * bf2f((ushort)(hv & 0xffffu));
        a1 += w * bf2f((ushort)(hv >> 16));
    }
    if (BF16OUT) {
        if (RELU) { a0 = fmaxf(a0, 0.f); a1 = fmaxf(a1, 0.f); }
        uint packed = (uint)f2bf(a0) | ((uint)f2bf(a1) << 16);
        ((uint*)out)[(long)node * L + c] = packed;
    } else {
        float2 r; r.x = a0; r.y = a1;
        ((float2*)out)[(long)node * L + c] = r;
    }
}

extern "C" void kernel_launch(void* const* d_in, const int* in_sizes, int n_in,
                              void* d_out, int out_size, void* d_ws, size_t ws_size,
                              hipStream_t stream) {
    const float* x   = (const float*)d_in[0];
    const void*  ei1 = d_in[1];
    const void*  ei2 = d_in[2];
    const float* ew1 = (const float*)d_in[3];
    const float* ew2 = (const float*)d_in[4];
    const float* W1  = (const float*)d_in[5];   // [128,256] fp32
    const float* W2  = (const float*)d_in[6];   // [64,128]  fp32

    const int N = in_sizes[0] / 256;   // 100000
    const int E = in_sizes[3];         // 1600000
    const int NB = (N + 255) / 256;    // scan blocks (391)
    const int EB = (E + 255) / 256;    // edge blocks (6250)

    // workspace carve-up
    char* ws = (char*)d_ws;
    size_t off = 0;
    ushort* XW     = (ushort*)(ws + off); off += (size_t)N * 128 * 2;  // 25.6MB (also H2)
    ushort* hbuf   = (ushort*)(ws + off); off += (size_t)N * 128 * 2;  // 25.6MB
    int2*   pairs  = (int2*)  (ws + off); off += (size_t)E * 8;        // 12.8MB
    int*    deg    = (int*)   (ws + off); off += (size_t)N * 4;
    int*    rowptr = (int*)   (ws + off); off += (size_t)(N + 1) * 4;
    int*    cursor = (int*)   (ws + off); off += (size_t)N * 4;
    int*    bsum   = (int*)   (ws + off); off += 512 * 4;
    int*    boff   = (int*)   (ws + off); off += 512 * 4;
    ushort* w1b    = (ushort*)(ws + off); off += 128 * 256 * 2;
    ushort* w2b    = (ushort*)(ws + off); off += 64 * 128 * 2;
    int*    flag   = (int*)   (ws + off);
    ushort* H2     = XW;   // XW dead after gather1

    detect_i64<<<1, 64, 0, stream>>>((const uint*)ei1, flag);
    cvt_w<<<(128 * 256 + 64 * 128 + 255) / 256, 256, 0, stream>>>(
        W1, W2, w1b, w2b, 128 * 256, 64 * 128);

    int gblocks = (N + 255) / 256;
    gemm_bt<256, 128, true><<<gblocks, 256, 0, stream>>>(x, w1b, XW, N);

    // ---- layer 1 CSR + gather (fused relu + bf16 cast) ----
    hipMemsetAsync(deg, 0, (size_t)N * 4, stream);
    hist_dst<<<EB, 256, 0, stream>>>(ei1, deg, E, flag);
    block_sum<<<NB, 256, 0, stream>>>(deg, bsum, N);
    scan_bsum<<<1, 512, 0, stream>>>(bsum, boff, NB);
    scan_final<<<NB, 256, 0, stream>>>(deg, boff, rowptr, N, E);
    hipMemcpyAsync(cursor, rowptr, (size_t)N * 4, hipMemcpyDeviceToDevice, stream);
    fill_pairs<<<EB, 256, 0, stream>>>(ei1, ew1, cursor, pairs, E, flag);
    gather_nodes<128, true, true><<<(N * 1 + 3) / 4, 256, 0, stream>>>(
        XW, pairs, rowptr, hbuf, N);   // 1 node/wave, 4 waves/block

    // ---- layer 2 ----
    gemm_bt<128, 64, false><<<gblocks, 256, 0, stream>>>(hbuf, w2b, H2, N);
    hipMemsetAsync(deg, 0, (size_t)N * 4, stream);
    hist_dst<<<EB, 256, 0, stream>>>(ei2, deg, E, flag);
    block_sum<<<NB, 256, 0, stream>>>(deg, bsum, N);
    scan_bsum<<<1, 512, 0, stream>>>(bsum, boff, NB);
    scan_final<<<NB, 256, 0, stream>>>(deg, boff, rowptr, N, E);
    hipMemcpyAsync(cursor, rowptr, (size_t)N * 4, hipMemcpyDeviceToDevice, stream);
    fill_pairs<<<EB, 256, 0, stream>>>(ei2, ew2, cursor, pairs, E, flag);
    gather_nodes<64, false, false><<<(N * 2 + 7) / 8, 256, 0, stream>>>(
        H2, pairs, rowptr, (float*)d_out, N);   // 2 nodes/wave
}

// Round 4
// 702.613 us; speedup vs baseline: 3.1294x; 1.2005x over previous
//
#include <hip/hip_runtime.h>

typedef __attribute__((ext_vector_type(8))) short short8;
typedef __attribute__((ext_vector_type(4))) float floatx4;

__device__ __forceinline__ ushort f2bf(float f) {
    uint u = __builtin_bit_cast(uint, f);
    uint r = (u + 0x7FFFu + ((u >> 16) & 1u)) >> 16;   // RNE; inputs finite
    return (ushort)r;
}
__device__ __forceinline__ float bf2f(ushort u) {
    return __builtin_bit_cast(float, (uint)u << 16);
}

// Detect whether edge_index arrived as int64 (odd 32-bit words all zero) or int32.
__global__ void detect_i64(const uint* __restrict__ p, int* __restrict__ flag) {
    uint v = p[2 * threadIdx.x + 1];
    unsigned long long b = __ballot(v != 0u);
    if (threadIdx.x == 0) *flag = (b == 0ull) ? 1 : 0;
}

// Convert the (small) weight matrices fp32 -> bf16 once.
__global__ __launch_bounds__(256) void cvt_w(const float* __restrict__ W1,
                                             const float* __restrict__ W2,
                                             ushort* __restrict__ w1b,
                                             ushort* __restrict__ w2b, int n1, int n2) {
    int i = blockIdx.x * 256 + threadIdx.x;
    if (i < n1) w1b[i] = f2bf(W1[i]);
    else if (i < n1 + n2) w2b[i - n1] = f2bf(W2[i - n1]);
}

// Y[N,NOUT] = X[N,K] @ W[NOUT,K]^T   (X fp32 or bf16, W bf16, fp32 MFMA accum, bf16 out)
template<int K, int NOUT, bool XF32>
__global__ __launch_bounds__(256) void gemm_bt(const void* __restrict__ Xv,
                                               const ushort* __restrict__ W,
                                               ushort* __restrict__ Y, int N) {
    constexpr int NT = NOUT / 16;
    constexpr int KS = K / 32;
    const int lane = threadIdx.x & 63;
    const int wv   = threadIdx.x >> 6;
    const int t    = lane & 15;
    const int q    = lane >> 4;
    const int rbase = (blockIdx.x * 4 + wv) * 64;
    if (rbase >= N) return;

    floatx4 acc[4][NT];
    #pragma unroll
    for (int a = 0; a < 4; a++)
        #pragma unroll
        for (int b = 0; b < NT; b++)
            #pragma unroll
            for (int i = 0; i < 4; i++) acc[a][b][i] = 0.f;

    for (int ks = 0; ks < KS; ks++) {
        short8 af[4];
        #pragma unroll
        for (int rt = 0; rt < 4; rt++) {
            int row = rbase + rt * 16 + t;
            if (row < N) {
                if (XF32) {
                    const float* p = (const float*)Xv + (long)row * K + ks * 32 + q * 8;
                    float4 a0 = *(const float4*)p;
                    float4 a1 = *(const float4*)(p + 4);
                    af[rt][0] = (short)f2bf(a0.x); af[rt][1] = (short)f2bf(a0.y);
                    af[rt][2] = (short)f2bf(a0.z); af[rt][3] = (short)f2bf(a0.w);
                    af[rt][4] = (short)f2bf(a1.x); af[rt][5] = (short)f2bf(a1.y);
                    af[rt][6] = (short)f2bf(a1.z); af[rt][7] = (short)f2bf(a1.w);
                } else {
                    af[rt] = *(const short8*)((const ushort*)Xv + (long)row * K + ks * 32 + q * 8);
                }
            } else {
                #pragma unroll
                for (int i = 0; i < 8; i++) af[rt][i] = 0;
            }
        }
        #pragma unroll
        for (int nt = 0; nt < NT; nt++) {
            short8 bf = *(const short8*)(W + (long)(nt * 16 + t) * K + ks * 32 + q * 8);
            #pragma unroll
            for (int rt = 0; rt < 4; rt++)
                acc[rt][nt] = __builtin_amdgcn_mfma_f32_16x16x32_bf16(af[rt], bf, acc[rt][nt], 0, 0, 0);
        }
    }
    #pragma unroll
    for (int rt = 0; rt < 4; rt++) {
        #pragma unroll
        for (int j = 0; j < 4; j++) {
            int row = rbase + rt * 16 + q * 4 + j;
            if (row < N) {
                #pragma unroll
                for (int nt = 0; nt < NT; nt++)
                    Y[(long)row * NOUT + nt * 16 + t] = f2bf(acc[rt][nt][j]);
            }
        }
    }
}

// ---- CSR build ----
__global__ __launch_bounds__(256) void hist_dst(const void* __restrict__ eidx,
                                                int* __restrict__ deg, int E,
                                                const int* __restrict__ flag) {
    int e = blockIdx.x * 256 + threadIdx.x;
    if (e >= E) return;
    int dst;
    if (*flag) dst = (int)((const long long*)eidx)[e + E];
    else       dst = ((const int*)eidx)[e + E];
    atomicAdd(deg + dst, 1);
}

__global__ __launch_bounds__(256) void block_sum(const int* __restrict__ deg,
                                                 int* __restrict__ bsum, int N) {
    __shared__ int s[4];
    int i = blockIdx.x * 256 + threadIdx.x;
    int v = (i < N) ? deg[i] : 0;
    #pragma unroll
    for (int off = 32; off; off >>= 1) v += __shfl_down(v, off, 64);
    int wv = threadIdx.x >> 6;
    if ((threadIdx.x & 63) == 0) s[wv] = v;
    __syncthreads();
    if (threadIdx.x == 0) bsum[blockIdx.x] = s[0] + s[1] + s[2] + s[3];
}

__global__ __launch_bounds__(512) void scan_bsum(const int* __restrict__ bsum,
                                                 int* __restrict__ boff, int nb) {
    __shared__ int s[512];
    int t = threadIdx.x;
    s[t] = (t < nb) ? bsum[t] : 0;
    __syncthreads();
    for (int off = 1; off < 512; off <<= 1) {
        int v = (t >= off) ? s[t - off] : 0;
        __syncthreads();
        s[t] += v;
        __syncthreads();
    }
    if (t < nb) boff[t] = (t == 0) ? 0 : s[t - 1];
}

__global__ __launch_bounds__(256) void scan_final(const int* __restrict__ deg,
                                                  const int* __restrict__ boff,
                                                  int* __restrict__ rowptr, int N, int E) {
    __shared__ int s[256];
    int b = blockIdx.x, t = threadIdx.x;
    int i = b * 256 + t;
    s[t] = (i < N) ? deg[i] : 0;
    __syncthreads();
    for (int off = 1; off < 256; off <<= 1) {
        int v = (t >= off) ? s[t - off] : 0;
        __syncthreads();
        s[t] += v;
        __syncthreads();
    }
    if (i < N) rowptr[i] = boff[b] + (t ? s[t - 1] : 0);
    if (b == 0 && t == 0) rowptr[N] = E;
}

__global__ __launch_bounds__(256) void fill_pairs(const void* __restrict__ eidx,
                                                  const float* __restrict__ ew,
                                                  int* __restrict__ cursor,
                                                  int2* __restrict__ pairs, int E,
                                                  const int* __restrict__ flag) {
    int e = blockIdx.x * 256 + threadIdx.x;
    if (e >= E) return;
    int src, dst;
    if (*flag) {
        const long long* p = (const long long*)eidx;
        src = (int)p[e]; dst = (int)p[e + E];
    } else {
        const int* p = (const int*)eidx;
        src = p[e]; dst = p[e + E];
    }
    int pos = atomicAdd(cursor + dst, 1);
    pairs[pos] = make_int2(src, __builtin_bit_cast(int, ew[e]));
}

// ---- Pull gather: out[i] = sum_e w_e * H[src_e]  (fp32 accum in regs) ----
// F feats; L = F/2 lanes per node (2 bf16 feats per lane); 64/L nodes per wave.
// 4-wide edge unroll: 4 independent H-row loads in flight per iteration to
// break the load->load dependency chain (round-3 profile: VALUBusy 20%,
// HBM 17% -> latency-bound). Tail edges are clamped to e-1 with weight 0.
template<int F, bool RELU, bool BF16OUT>
__global__ __launch_bounds__(256) void gather_nodes(const ushort* __restrict__ H,
                                                    const int2* __restrict__ pairs,
                                                    const int* __restrict__ rowptr,
                                                    void* __restrict__ out, int N) {
    constexpr int L = F / 2;
    constexpr int NPW = 64 / L;
    int wave = (blockIdx.x * 256 + threadIdx.x) >> 6;
    int lane = threadIdx.x & 63;
    int node = wave * NPW + lane / L;
    int c = lane % L;
    if (node >= N) return;
    int s = rowptr[node], e = rowptr[node + 1];
    float a0 = 0.f, a1 = 0.f, b0 = 0.f, b1 = 0.f;
    float c0 = 0.f, c1 = 0.f, d0 = 0.f, d1 = 0.f;
    for (int i = s; i < e; i += 4) {
        int i1 = min(i + 1, e - 1), i2 = min(i + 2, e - 1), i3 = min(i + 3, e - 1);
        int2 p0 = pairs[i];
        int2 p1 = pairs[i1];
        int2 p2 = pairs[i2];
        int2 p3 = pairs[i3];
        uint h0 = *(const uint*)(H + (long)p0.x * F + 2 * c);
        uint h1 = *(const uint*)(H + (long)p1.x * F + 2 * c);
        uint h2 = *(const uint*)(H + (long)p2.x * F + 2 * c);
        uint h3 = *(const uint*)(H + (long)p3.x * F + 2 * c);
        float w0 = __builtin_bit_cast(float, p0.y);
        float w1 = (i + 1 < e) ? __builtin_bit_cast(float, p1.y) : 0.f;
        float w2 = (i + 2 < e) ? __builtin_bit_cast(float, p2.y) : 0.f;
        float w3 = (i + 3 < e) ? __builtin_bit_cast(float, p3.y) : 0.f;
        a0 += w0 * bf2f((ushort)(h0 & 0xffffu));  a1 += w0 * bf2f((ushort)(h0 >> 16));
        b0 += w1 * bf2f((ushort)(h1 & 0xffffu));  b1 += w1 * bf2f((ushort)(h1 >> 16));
        c0 += w2 * bf2f((ushort)(h2 & 0xffffu));  c1 += w2 * bf2f((ushort)(h2 >> 16));
        d0 += w3 * bf2f((ushort)(h3 & 0xffffu));  d1 += w3 * bf2f((ushort)(h3 >> 16));
    }
    float r0 = (a0 + b0) + (c0 + d0);
    float r1 = (a1 + b1) + (c1 + d1);
    if (BF16OUT) {
        if (RELU) { r0 = fmaxf(r0, 0.f); r1 = fmaxf(r1, 0.f); }
        uint packed = (uint)f2bf(r0) | ((uint)f2bf(r1) << 16);
        ((uint*)out)[(long)node * L + c] = packed;
    } else {
        float2 r; r.x = r0; r.y = r1;
        ((float2*)out)[(long)node * L + c] = r;
    }
}

extern "C" void kernel_launch(void* const* d_in, const int* in_sizes, int n_in,
                              void* d_out, int out_size, void* d_ws, size_t ws_size,
                              hipStream_t stream) {
    const float* x   = (const float*)d_in[0];
    const void*  ei1 = d_in[1];
    const void*  ei2 = d_in[2];
    const float* ew1 = (const float*)d_in[3];
    const float* ew2 = (const float*)d_in[4];
    const float* W1  = (const float*)d_in[5];   // [128,256] fp32
    const float* W2  = (const float*)d_in[6];   // [64,128]  fp32

    const int N = in_sizes[0] / 256;   // 100000
    const int E = in_sizes[3];         // 1600000
    const int NB = (N + 255) / 256;    // scan blocks (391)
    const int EB = (E + 255) / 256;    // edge blocks (6250)

    // workspace carve-up
    char* ws = (char*)d_ws;
    size_t off = 0;
    ushort* XW     = (ushort*)(ws + off); off += (size_t)N * 128 * 2;  // 25.6MB (also H2)
    ushort* hbuf   = (ushort*)(ws + off); off += (size_t)N * 128 * 2;  // 25.6MB
    int2*   pairs  = (int2*)  (ws + off); off += (size_t)E * 8;        // 12.8MB
    int*    deg    = (int*)   (ws + off); off += (size_t)N * 4;
    int*    rowptr = (int*)   (ws + off); off += (size_t)(N + 1) * 4;
    int*    cursor = (int*)   (ws + off); off += (size_t)N * 4;
    int*    bsum   = (int*)   (ws + off); off += 512 * 4;
    int*    boff   = (int*)   (ws + off); off += 512 * 4;
    ushort* w1b    = (ushort*)(ws + off); off += 128 * 256 * 2;
    ushort* w2b    = (ushort*)(ws + off); off += 64 * 128 * 2;
    int*    flag   = (int*)   (ws + off);
    ushort* H2     = XW;   // XW dead after gather1

    detect_i64<<<1, 64, 0, stream>>>((const uint*)ei1, flag);
    cvt_w<<<(128 * 256 + 64 * 128 + 255) / 256, 256, 0, stream>>>(
        W1, W2, w1b, w2b, 128 * 256, 64 * 128);

    int gblocks = (N + 255) / 256;
    gemm_bt<256, 128, true><<<gblocks, 256, 0, stream>>>(x, w1b, XW, N);

    // ---- layer 1 CSR + gather (fused relu + bf16 cast) ----
    hipMemsetAsync(deg, 0, (size_t)N * 4, stream);
    hist_dst<<<EB, 256, 0, stream>>>(ei1, deg, E, flag);
    block_sum<<<NB, 256, 0, stream>>>(deg, bsum, N);
    scan_bsum<<<1, 512, 0, stream>>>(bsum, boff, NB);
    scan_final<<<NB, 256, 0, stream>>>(deg, boff, rowptr, N, E);
    hipMemcpyAsync(cursor, rowptr, (size_t)N * 4, hipMemcpyDeviceToDevice, stream);
    fill_pairs<<<EB, 256, 0, stream>>>(ei1, ew1, cursor, pairs, E, flag);
    gather_nodes<128, true, true><<<(N * 1 + 3) / 4, 256, 0, stream>>>(
        XW, pairs, rowptr, hbuf, N);   // 1 node/wave, 4 waves/block

    // ---- layer 2 ----
    gemm_bt<128, 64, false><<<gblocks, 256, 0, stream>>>(hbuf, w2b, H2, N);
    hipMemsetAsync(deg, 0, (size_t)N * 4, stream);
    hist_dst<<<EB, 256, 0, stream>>>(ei2, deg, E, flag);
    block_sum<<<NB, 256, 0, stream>>>(deg, bsum, N);
    scan_bsum<<<1, 512, 0, stream>>>(bsum, boff, NB);
    scan_final<<<NB, 256, 0, stream>>>(deg, boff, rowptr, N, E);
    hipMemcpyAsync(cursor, rowptr, (size_t)N * 4, hipMemcpyDeviceToDevice, stream);
    fill_pairs<<<EB, 256, 0, stream>>>(ei2, ew2, cursor, pairs, E, flag);
    gather_nodes<64, false, false><<<(N * 2 + 7) / 8, 256, 0, stream>>>(
        H2, pairs, rowptr, (float*)d_out, N);   // 2 nodes/wave
}

// Round 5
// 522.324 us; speedup vs baseline: 4.2096x; 1.3452x over previous
//
#include <hip/hip_runtime.h>

typedef __attribute__((ext_vector_type(8))) short short8;
typedef __attribute__((ext_vector_type(4))) float floatx4;

// Bucket geometry: 256 dst-nodes per bucket (dl = dst & 255 packed in bits 24..31
// of pairs.x; requires src < 2^24 and N <= 131072 -- true here: N=100000).
#define BKT_SHIFT 8
#define BKT_MASK 255
#define SORT_CAP 6144   // LDS edge capacity per bucket (avg 4092, sigma ~64)

__device__ __forceinline__ ushort f2bf(float f) {
    uint u = __builtin_bit_cast(uint, f);
    uint r = (u + 0x7FFFu + ((u >> 16) & 1u)) >> 16;   // RNE; inputs finite
    return (ushort)r;
}
__device__ __forceinline__ float bf2f(ushort u) {
    return __builtin_bit_cast(float, (uint)u << 16);
}

// Detect whether edge_index arrived as int64 (odd 32-bit words all zero) or int32.
__global__ void detect_i64(const uint* __restrict__ p, int* __restrict__ flag) {
    uint v = p[2 * threadIdx.x + 1];
    unsigned long long b = __ballot(v != 0u);
    if (threadIdx.x == 0) *flag = (b == 0ull) ? 1 : 0;
}

// Convert the (small) weight matrices fp32 -> bf16 once.
__global__ __launch_bounds__(256) void cvt_w(const float* __restrict__ W1,
                                             const float* __restrict__ W2,
                                             ushort* __restrict__ w1b,
                                             ushort* __restrict__ w2b, int n1, int n2) {
    int i = blockIdx.x * 256 + threadIdx.x;
    if (i < n1) w1b[i] = f2bf(W1[i]);
    else if (i < n1 + n2) w2b[i - n1] = f2bf(W2[i - n1]);
}

// Y[N,NOUT] = X[N,K] @ W[NOUT,K]^T   (X fp32 or bf16, W bf16, fp32 MFMA accum, bf16 out)
template<int K, int NOUT, bool XF32>
__global__ __launch_bounds__(256) void gemm_bt(const void* __restrict__ Xv,
                                               const ushort* __restrict__ W,
                                               ushort* __restrict__ Y, int N) {
    constexpr int NT = NOUT / 16;
    constexpr int KS = K / 32;
    const int lane = threadIdx.x & 63;
    const int wv   = threadIdx.x >> 6;
    const int t    = lane & 15;
    const int q    = lane >> 4;
    const int rbase = (blockIdx.x * 4 + wv) * 64;
    if (rbase >= N) return;

    floatx4 acc[4][NT];
    #pragma unroll
    for (int a = 0; a < 4; a++)
        #pragma unroll
        for (int b = 0; b < NT; b++)
            #pragma unroll
            for (int i = 0; i < 4; i++) acc[a][b][i] = 0.f;

    for (int ks = 0; ks < KS; ks++) {
        short8 af[4];
        #pragma unroll
        for (int rt = 0; rt < 4; rt++) {
            int row = rbase + rt * 16 + t;
            if (row < N) {
                if (XF32) {
                    const float* p = (const float*)Xv + (long)row * K + ks * 32 + q * 8;
                    float4 a0 = *(const float4*)p;
                    float4 a1 = *(const float4*)(p + 4);
                    af[rt][0] = (short)f2bf(a0.x); af[rt][1] = (short)f2bf(a0.y);
                    af[rt][2] = (short)f2bf(a0.z); af[rt][3] = (short)f2bf(a0.w);
                    af[rt][4] = (short)f2bf(a1.x); af[rt][5] = (short)f2bf(a1.y);
                    af[rt][6] = (short)f2bf(a1.z); af[rt][7] = (short)f2bf(a1.w);
                } else {
                    af[rt] = *(const short8*)((const ushort*)Xv + (long)row * K + ks * 32 + q * 8);
                }
            } else {
                #pragma unroll
                for (int i = 0; i < 8; i++) af[rt][i] = 0;
            }
        }
        #pragma unroll
        for (int nt = 0; nt < NT; nt++) {
            short8 bf = *(const short8*)(W + (long)(nt * 16 + t) * K + ks * 32 + q * 8);
            #pragma unroll
            for (int rt = 0; rt < 4; rt++)
                acc[rt][nt] = __builtin_amdgcn_mfma_f32_16x16x32_bf16(af[rt], bf, acc[rt][nt], 0, 0, 0);
        }
    }
    #pragma unroll
    for (int rt = 0; rt < 4; rt++) {
        #pragma unroll
        for (int j = 0; j < 4; j++) {
            int row = rbase + rt * 16 + q * 4 + j;
            if (row < N) {
                #pragma unroll
                for (int nt = 0; nt < NT; nt++)
                    Y[(long)row * NOUT + nt * 16 + t] = f2bf(acc[rt][nt][j]);
            }
        }
    }
}

// ---- CSR build, two-level counting sort ----
// Level 0: coarse-bucket histogram (LDS pre-reduce -> low-contention global adds).
__global__ __launch_bounds__(256) void bucket_hist(const void* __restrict__ eidx,
                                                   int* __restrict__ bhist, int E, int nbk,
                                                   const int* __restrict__ flag) {
    __shared__ int lc[512];
    for (int t = threadIdx.x; t < 512; t += 256) lc[t] = 0;
    __syncthreads();
    int S = (E + gridDim.x - 1) / gridDim.x;
    int s = blockIdx.x * S, e = min(E, s + S);
    bool f = *flag;
    for (int i = s + threadIdx.x; i < e; i += 256) {
        int dst = f ? (int)((const long long*)eidx)[i + E] : ((const int*)eidx)[i + E];
        atomicAdd(&lc[dst >> BKT_SHIFT], 1);
    }
    __syncthreads();
    for (int t = threadIdx.x; t < nbk; t += 256)
        if (lc[t]) atomicAdd(&bhist[t], lc[t]);
}

// Exclusive scan over <=512 bucket counts -> segment starts (+cursor copy).
__global__ __launch_bounds__(512) void bucket_scan(const int* __restrict__ bhist,
                                                   int* __restrict__ segstart,
                                                   int* __restrict__ cursor, int nbk, int E) {
    __shared__ int s[512];
    int t = threadIdx.x;
    s[t] = (t < nbk) ? bhist[t] : 0;
    __syncthreads();
    for (int off = 1; off < 512; off <<= 1) {
        int v = (t >= off) ? s[t - off] : 0;
        __syncthreads();
        s[t] += v;
        __syncthreads();
    }
    int ex = t ? s[t - 1] : 0;
    if (t < nbk) { segstart[t] = ex; cursor[t] = ex; }
    if (t == 0) segstart[nbk] = E;
}

// Level 1: bin edges into bucket segments. Each block owns a contiguous edge
// slice; per-(block,bucket) chunks (~16 edges = 128B) are reserved with ONE
// global atomic and written back-to-back -> ~1.3x write amp vs the 8x of a
// per-edge scattered CSR fill (round-4 profile: fill_pairs WRITE_SIZE 100MB).
__global__ __launch_bounds__(256) void bin_edges(const void* __restrict__ eidx,
                                                 const float* __restrict__ ew,
                                                 int* __restrict__ cursor,
                                                 int2* __restrict__ binA, int E, int nbk,
                                                 const int* __restrict__ flag) {
    __shared__ int lc[512], lb[512], lo[512];
    for (int t = threadIdx.x; t < 512; t += 256) { lc[t] = 0; lo[t] = 0; }
    __syncthreads();
    int S = (E + gridDim.x - 1) / gridDim.x;
    int s = blockIdx.x * S, e = min(E, s + S);
    bool f = *flag;
    for (int i = s + threadIdx.x; i < e; i += 256) {
        int dst = f ? (int)((const long long*)eidx)[i + E] : ((const int*)eidx)[i + E];
        atomicAdd(&lc[dst >> BKT_SHIFT], 1);
    }
    __syncthreads();
    for (int t = threadIdx.x; t < nbk; t += 256)
        lb[t] = lc[t] ? atomicAdd(&cursor[t], lc[t]) : 0;
    __syncthreads();
    for (int i = s + threadIdx.x; i < e; i += 256) {
        int src, dst;
        if (f) { const long long* p = (const long long*)eidx; src = (int)p[i]; dst = (int)p[i + E]; }
        else   { const int* p = (const int*)eidx;             src = p[i];      dst = p[i + E]; }
        int bk = dst >> BKT_SHIFT;
        int off = atomicAdd(&lo[bk], 1);
        binA[lb[bk] + off] = make_int2(src | ((dst & BKT_MASK) << 24),
                                       __builtin_bit_cast(int, ew[i]));
    }
}

// Level 2: exact CSR within each bucket via LDS counting sort; coalesced
// write-out; emits rowptr as a by-product. Fallback path (segment > SORT_CAP)
// places directly to global -- correct for any degree distribution.
__global__ __launch_bounds__(256) void sort_bucket(const int2* __restrict__ binA,
                                                   const int* __restrict__ segstart,
                                                   int2* __restrict__ pairs,
                                                   int* __restrict__ rowptr,
                                                   int N, int E, int nbk) {
    __shared__ int cnt[256], cur[256];
    __shared__ int2 ps[SORT_CAP];
    int b = blockIdx.x, t = threadIdx.x;
    int s = segstart[b], e = segstart[b + 1];
    int n = e - s;
    cnt[t] = 0; cur[t] = 0;
    __syncthreads();
    for (int i = s + t; i < e; i += 256)
        atomicAdd(&cnt[(uint)binA[i].x >> 24], 1);
    __syncthreads();
    for (int off = 1; off < 256; off <<= 1) {      // inclusive scan
        int v = (t >= off) ? cnt[t - off] : 0;
        __syncthreads();
        cnt[t] += v;
        __syncthreads();
    }
    int node = (b << BKT_SHIFT) + t;
    int ex = t ? cnt[t - 1] : 0;
    if (node < N) rowptr[node] = s + ex;
    if (node == N || (b == nbk - 1 && t == 255)) rowptr[N] = E;
    __syncthreads();
    if (n <= SORT_CAP) {
        for (int i = s + t; i < e; i += 256) {
            int2 p = binA[i];
            int dl = (uint)p.x >> 24;
            int pos = (dl ? cnt[dl - 1] : 0) + atomicAdd(&cur[dl], 1);
            ps[pos] = make_int2(p.x & 0x00FFFFFF, p.y);
        }
        __syncthreads();
        for (int j = t; j < n; j += 256) pairs[s + j] = ps[j];
    } else {
        for (int i = s + t; i < e; i += 256) {
            int2 p = binA[i];
            int dl = (uint)p.x >> 24;
            int pos = s + (dl ? cnt[dl - 1] : 0) + atomicAdd(&cur[dl], 1);
            pairs[pos] = make_int2(p.x & 0x00FFFFFF, p.y);
        }
    }
}

// ---- Pull gather: out[i] = sum_e w_e * H[src_e]  (fp32 accum in regs) ----
// 4-wide edge unroll to break the load->load latency chain.
template<int F, bool RELU, bool BF16OUT>
__global__ __launch_bounds__(256) void gather_nodes(const ushort* __restrict__ H,
                                                    const int2* __restrict__ pairs,
                                                    const int* __restrict__ rowptr,
                                                    void* __restrict__ out, int N) {
    constexpr int L = F / 2;
    constexpr int NPW = 64 / L;
    int wave = (blockIdx.x * 256 + threadIdx.x) >> 6;
    int lane = threadIdx.x & 63;
    int node = wave * NPW + lane / L;
    int c = lane % L;
    if (node >= N) return;
    int s = rowptr[node], e = rowptr[node + 1];
    float a0 = 0.f, a1 = 0.f, b0 = 0.f, b1 = 0.f;
    float c0 = 0.f, c1 = 0.f, d0 = 0.f, d1 = 0.f;
    for (int i = s; i < e; i += 4) {
        int i1 = min(i + 1, e - 1), i2 = min(i + 2, e - 1), i3 = min(i + 3, e - 1);
        int2 p0 = pairs[i];
        int2 p1 = pairs[i1];
        int2 p2 = pairs[i2];
        int2 p3 = pairs[i3];
        uint h0 = *(const uint*)(H + (long)p0.x * F + 2 * c);
        uint h1 = *(const uint*)(H + (long)p1.x * F + 2 * c);
        uint h2 = *(const uint*)(H + (long)p2.x * F + 2 * c);
        uint h3 = *(const uint*)(H + (long)p3.x * F + 2 * c);
        float w0 = __builtin_bit_cast(float, p0.y);
        float w1 = (i + 1 < e) ? __builtin_bit_cast(float, p1.y) : 0.f;
        float w2 = (i + 2 < e) ? __builtin_bit_cast(float, p2.y) : 0.f;
        float w3 = (i + 3 < e) ? __builtin_bit_cast(float, p3.y) : 0.f;
        a0 += w0 * bf2f((ushort)(h0 & 0xffffu));  a1 += w0 * bf2f((ushort)(h0 >> 16));
        b0 += w1 * bf2f((ushort)(h1 & 0xffffu));  b1 += w1 * bf2f((ushort)(h1 >> 16));
        c0 += w2 * bf2f((ushort)(h2 & 0xffffu));  c1 += w2 * bf2f((ushort)(h2 >> 16));
        d0 += w3 * bf2f((ushort)(h3 & 0xffffu));  d1 += w3 * bf2f((ushort)(h3 >> 16));
    }
    float r0 = (a0 + b0) + (c0 + d0);
    float r1 = (a1 + b1) + (c1 + d1);
    if (BF16OUT) {
        if (RELU) { r0 = fmaxf(r0, 0.f); r1 = fmaxf(r1, 0.f); }
        uint packed = (uint)f2bf(r0) | ((uint)f2bf(r1) << 16);
        ((uint*)out)[(long)node * L + c] = packed;
    } else {
        float2 r; r.x = r0; r.y = r1;
        ((float2*)out)[(long)node * L + c] = r;
    }
}

extern "C" void kernel_launch(void* const* d_in, const int* in_sizes, int n_in,
                              void* d_out, int out_size, void* d_ws, size_t ws_size,
                              hipStream_t stream) {
    const float* x   = (const float*)d_in[0];
    const void*  ei1 = d_in[1];
    const void*  ei2 = d_in[2];
    const float* ew1 = (const float*)d_in[3];
    const float* ew2 = (const float*)d_in[4];
    const float* W1  = (const float*)d_in[5];   // [128,256] fp32
    const float* W2  = (const float*)d_in[6];   // [64,128]  fp32

    const int N = in_sizes[0] / 256;   // 100000
    const int E = in_sizes[3];         // 1600000
    const int NBK = (N + 255) >> 8;    // 391 coarse buckets

    // workspace carve-up (binA aliases hbuf: binA dead before gather1 writes hbuf;
    // hbuf dead before layer-2 bin_edges rewrites the region)
    char* ws = (char*)d_ws;
    size_t off = 0;
    ushort* XW     = (ushort*)(ws + off); off += (size_t)N * 128 * 2;  // 25.6MB (also H2)
    char*   hbufrg = ws + off;            off += (size_t)N * 128 * 2;  // 25.6MB (hbuf | binA)
    int2*   pairs  = (int2*)  (ws + off); off += (size_t)E * 8;        // 12.8MB
    int*    rowptr = (int*)   (ws + off); off += (size_t)(N + 1) * 4;
    int*    bhist  = (int*)   (ws + off); off += 512 * 4;
    int*    segst  = (int*)   (ws + off); off += 513 * 4;
    int*    cursor = (int*)   (ws + off); off += 513 * 4;
    ushort* w1b    = (ushort*)(ws + off); off += 128 * 256 * 2;
    ushort* w2b    = (ushort*)(ws + off); off += 64 * 128 * 2;
    int*    flag   = (int*)   (ws + off);
    ushort* hbuf   = (ushort*)hbufrg;
    int2*   binA   = (int2*)hbufrg;
    ushort* H2     = XW;

    detect_i64<<<1, 64, 0, stream>>>((const uint*)ei1, flag);
    cvt_w<<<(128 * 256 + 64 * 128 + 255) / 256, 256, 0, stream>>>(
        W1, W2, w1b, w2b, 128 * 256, 64 * 128);

    int gblocks = (N + 255) / 256;
    gemm_bt<256, 128, true><<<gblocks, 256, 0, stream>>>(x, w1b, XW, N);

    // ---- layer 1: CSR build + gather (fused relu + bf16 cast) ----
    hipMemsetAsync(bhist, 0, 512 * 4, stream);
    bucket_hist<<<256, 256, 0, stream>>>(ei1, bhist, E, NBK, flag);
    bucket_scan<<<1, 512, 0, stream>>>(bhist, segst, cursor, NBK, E);
    bin_edges<<<256, 256, 0, stream>>>(ei1, ew1, cursor, binA, E, NBK, flag);
    sort_bucket<<<NBK, 256, 0, stream>>>(binA, segst, pairs, rowptr, N, E, NBK);
    gather_nodes<128, true, true><<<(N + 3) / 4, 256, 0, stream>>>(
        XW, pairs, rowptr, hbuf, N);

    // ---- layer 2 ----
    gemm_bt<128, 64, false><<<gblocks, 256, 0, stream>>>(hbuf, w2b, H2, N);
    hipMemsetAsync(bhist, 0, 512 * 4, stream);
    bucket_hist<<<256, 256, 0, stream>>>(ei2, bhist, E, NBK, flag);
    bucket_scan<<<1, 512, 0, stream>>>(bhist, segst, cursor, NBK, E);
    bin_edges<<<256, 256, 0, stream>>>(ei2, ew2, cursor, binA, E, NBK, flag);
    sort_bucket<<<NBK, 256, 0, stream>>>(binA, segst, pairs, rowptr, N, E, NBK);
    gather_nodes<64, false, false><<<(N * 2 + 7) / 8, 256, 0, stream>>>(
        H2, pairs, rowptr, (float*)d_out, N);
}